// Round 12
// baseline (174.972 us; speedup 1.0000x reference)
//
#include <hip/hip_runtime.h>
#include <math.h>

// Problem: images [64,256,256] f32 -> patches [16384][256] f32 (identity perm)
//          tokens [16384] = argmin_v ||patch - vocab[v]||^2, vocab [4096][256] f32
#define PS      16
#define D       256
#define V       4096
#define M       16384
#define NSPLIT  64              // V / 64 column groups (per-wave partials)
#define PAIR_CAP 1048576
// Scores packed as u32 keys: q = (u32)((s + 1024) * 512)  (20 bits), key =
// (q << 12) | col. min() on keys = argmin with lowest-index tie-break.
// fp16 score-diff error sigma ~3e-2; QMARGIN 130 quanta (=0.254) is ~8 sigma
// incl. trunc slack. Flagged (~4%) get exact fp64 on a candidate set provably
// containing the argmin.
#define QMARGIN 130

typedef _Float16 half8 __attribute__((ext_vector_type(8)));
typedef _Float16 half4 __attribute__((ext_vector_type(4)));
typedef float    f32x4 __attribute__((ext_vector_type(4)));

__device__ __forceinline__ void gload_lds16(const void* g, void* l) {
  __builtin_amdgcn_global_load_lds(
      (const __attribute__((address_space(1))) unsigned int*)g,
      (__attribute__((address_space(3))) unsigned int*)l, 16, 0, 0);
}

// Fragment-major layouts (halves):
//  Ah2[rowblk(256)][kt(8)][i(4)][q(4)][cl(16)][8] : row = rowblk*64+i*16+cl,
//      k = kt*32 + q*8 + h.   idx = rowblk*16384 + kt*2048 + i*512 + q*128 + cl*8 + h
//  Vh2[sp(16)][kt(8)][jb(16)][q(4)][cl(16)][8]    : col = sp*256+jb*16+cl,
//      k = kt*32 + q*8 + h.   idx = sp*65536 + kt*8192 + jb*512 + q*128 + cl*8 + h

// ---------------------------------------------------------------------------
// Kernel 1: fused prep. Blocks [0,4096): patchify (float4) + fragment-major
// fp16 copy. Blocks [4096,5120): vocab fragment-major fp16 + v2.
// ---------------------------------------------------------------------------
__global__ __launch_bounds__(256) void prep_kernel(
    const float* __restrict__ img, const float* __restrict__ vocab,
    float* __restrict__ outp, _Float16* __restrict__ Ah2,
    _Float16* __restrict__ Vh2, float* __restrict__ v2,
    int* __restrict__ paircount) {
  if (blockIdx.x < 4096) {
    if (blockIdx.x == 0 && threadIdx.x == 0) *paircount = 0;
    const int t  = blockIdx.x * 256 + threadIdx.x;   // M*D/4 threads
    const int o4 = t << 2;
    const int m   = o4 >> 8;           // global patch index
    const int d   = o4 & 255;          // k (multiple of 4)
    const int b   = m >> 8;
    const int n   = m & 255;
    const int py = n >> 4, px = n & 15, i = d >> 4, j = d & 15;
    const float4 v = *(const float4*)(img + (b << 16) + ((py * PS + i) << 8) + px * PS + j);
    *(float4*)(outp + o4) = v;
    half4 h = { (_Float16)v.x, (_Float16)v.y, (_Float16)v.z, (_Float16)v.w };
    const int fa = (m >> 6) * 16384 + (d >> 5) * 2048 + ((m >> 4) & 3) * 512 +
                   ((d >> 3) & 3) * 128 + (m & 15) * 8 + (d & 7);
    *(half4*)(Ah2 + fa) = h;
  } else {
    const int gtid = (blockIdx.x - 4096) * 256 + threadIdx.x;
    const int c    = gtid >> 6;        // vocab row
    const int lane = gtid & 63;
    const int d0   = lane << 2;        // k (multiple of 4)
    const float4 v = *(const float4*)(vocab + (size_t)c * D + d0);
    half4 h = { (_Float16)v.x, (_Float16)v.y, (_Float16)v.z, (_Float16)v.w };
    const int fv = (c >> 8) * 65536 + (d0 >> 5) * 8192 + ((c >> 4) & 15) * 512 +
                   ((d0 >> 3) & 3) * 128 + (c & 15) * 8 + (d0 & 7);
    *(half4*)(Vh2 + fv) = h;
    float s = v.x * v.x + v.y * v.y + v.z * v.z + v.w * v.w;
    #pragma unroll
    for (int off = 32; off > 0; off >>= 1) s += __shfl_down(s, off);
    if (lane == 0) v2[c] = s;
  }
}

// ---------------------------------------------------------------------------
// Kernel 2: fp16 MFMA score GEMM, TRANSPOSED output (S^T = vocab x patches).
// mfma(vocab_frag, patch_frag): C/D row=q*4+reg -> vocab idx, col=lane&15 ->
// patch row. Each lane holds 16 scores per patch row -> in-lane top-2 fold
// (zero shuffles), then 2-stage merge across the 4 q-lanes (vs R11's 4-stage
// x16 butterfly). A/B operand fragment layouts are identical per-lane, so
// all loads are byte-identical to R11 -- only intrinsic order + epilogue
// change. Block = 64 rows x 256 cols; wave = 64 rows x 64 cols.
// ---------------------------------------------------------------------------
__global__ __launch_bounds__(256, 4) void gemm_score_kernel(
    const _Float16* __restrict__ Ah2,  // fragment-major, see layout above
    const _Float16* __restrict__ Vh2,
    const float* __restrict__ v2,
    unsigned* __restrict__ pk1, unsigned* __restrict__ pk2) {
  __shared__ __align__(16) _Float16 Af[8 * 64 * 32];  // 32 KB, same layout as Ah2 blk

  const int tid  = threadIdx.x;
  const int lane = tid & 63;
  const int wid  = tid >> 6;
  const int rowblk = blockIdx.x;
  const int sp     = blockIdx.y;            // 256-col split
  const int row0 = rowblk * 64;
  const int col0 = sp * 256 + wid * 64;     // this wave's 64 vocab cols
  const int grp  = sp * 4 + wid;            // 64-col group id

  // ---- stage A tile: 8 x (64 lanes x 16B contiguous), one barrier ----
  {
    const _Float16* src = Ah2 + (size_t)rowblk * 16384 + wid * 4096 + lane * 8;
    _Float16* dst = Af + wid * 4096;        // wave-uniform; HW adds lane*16B
    #pragma unroll
    for (int t = 0; t < 8; ++t)
      gload_lds16(src + t * 512, dst + t * 512);
  }
  __syncthreads();

  const int cl = lane & 15;           // fragment row/col within 16
  const int q  = lane >> 4;           // quad: k-chunk selector
  const _Float16* Ak = Af + q * 128 + cl * 8;                       // patch frags
  const _Float16* Bk = Vh2 + (size_t)sp * 65536 + wid * 2048 + q * 128 + cl * 8;  // vocab frags

  f32x4 acc[4][4];                    // [i = vocab tile][j = patch tile]
  #pragma unroll
  for (int i = 0; i < 4; ++i)
    #pragma unroll
    for (int j = 0; j < 4; ++j) acc[i][j] = (f32x4){0.f, 0.f, 0.f, 0.f};

  #pragma unroll 1                    // bound live set (R6 lesson)
  for (int kt = 0; kt < 8; ++kt) {
    half8 av[4], bp[4];
    #pragma unroll
    for (int i = 0; i < 4; ++i) av[i] = *(const half8*)(Bk + i * 512);  // vocab (A-op)
    #pragma unroll
    for (int j = 0; j < 4; ++j) bp[j] = *(const half8*)(Ak + j * 512);  // patch (B-op)
    Bk += 8192; Ak += 2048;
    #pragma unroll
    for (int i = 0; i < 4; ++i)
      #pragma unroll
      for (int j = 0; j < 4; ++j)
        acc[i][j] = __builtin_amdgcn_mfma_f32_16x16x32_f16(av[i], bp[j], acc[i][j], 0, 0, 0);
  }

  // Epilogue (S^T). Lane (cl,q) holds, for patch row m = row0 + j*16 + cl,
  // scores of vocab cols v = col0 + i*16 + q*4 + r.
  // key_f = (score+1024)*512 = (v2+1024)*512 - 1024*acc
  float Cv[16];
  #pragma unroll
  for (int i = 0; i < 4; ++i) {
    const float4 vq = *(const float4*)(v2 + col0 + i * 16 + q * 4);
    #pragma unroll
    for (int r = 0; r < 4; ++r) Cv[i * 4 + r] = fmaf(vq[r], 512.0f, 524288.0f);
  }
  #pragma unroll
  for (int j = 0; j < 4; ++j) {
    unsigned K1 = 0xFFFFFFFFu, K2 = 0xFFFFFFFFu;
    #pragma unroll
    for (int i = 0; i < 4; ++i)
      #pragma unroll
      for (int r = 0; r < 4; ++r) {
        const unsigned key =
            ((unsigned)fmaf(-1024.0f, acc[i][j][r], Cv[i * 4 + r]) << 12) |
            (unsigned)(col0 + i * 16 + q * 4 + r);
        K2 = min(K2, max(K1, key));
        K1 = min(K1, key);
      }
    // merge across the 4 q-lanes holding this patch row (xor 16, 32)
    #pragma unroll
    for (int mask = 16; mask <= 32; mask <<= 1) {
      const unsigned o1 = (unsigned)__shfl_xor((int)K1, mask);
      const unsigned o2 = (unsigned)__shfl_xor((int)K2, mask);
      K2 = min(min(K2, o2), max(K1, o1));
      K1 = min(K1, o1);
    }
    if (q == 0) {
      pk1[(size_t)grp * M + row0 + j * 16 + cl] = K1;
      pk2[(size_t)grp * M + row0 + j * 16 + cl] = K2;
    }
  }
}

// ---------------------------------------------------------------------------
// Kernel 3: merge NSPLIT partials -> token; flagged patches emit fp64-rescore
// candidate pairs (second streaming pass, L2-hot). Inits minkey.
// ---------------------------------------------------------------------------
__global__ __launch_bounds__(256) void reduce_gather_kernel(
    const unsigned* __restrict__ pk1, const unsigned* __restrict__ pk2,
    float* __restrict__ tok, unsigned long long* __restrict__ minkey,
    unsigned* __restrict__ pairs, int* __restrict__ paircount) {
  const int m = blockIdx.x * 256 + threadIdx.x;
  unsigned K1 = 0xFFFFFFFFu, K2 = 0xFFFFFFFFu;
  for (int s = 0; s < NSPLIT; ++s) {
    const unsigned b1 = pk1[(size_t)s * M + m];
    const unsigned b2 = pk2[(size_t)s * M + m];
    K2 = min(min(K2, b2), max(K1, b1));
    K1 = min(K1, b1);
  }
  tok[m] = (float)(K1 & 4095u);
  minkey[m] = 0xFFFFFFFFFFFFFFFFull;
  if ((int)(K2 >> 12) - (int)(K1 >> 12) <= QMARGIN) {
    const int th = (int)(K1 >> 12) + QMARGIN;
    int cnt = 0;
    for (int s = 0; s < NSPLIT; ++s) {
      const unsigned b1 = pk1[(size_t)s * M + m];
      const unsigned b2 = pk2[(size_t)s * M + m];
      cnt += ((int)(b2 >> 12) <= th) ? 64
           : (((int)(b1 >> 12) <= th) ? 1 : 0);
    }
    int base = atomicAdd(paircount, cnt);
    if (base + cnt <= PAIR_CAP) {
      const unsigned mh = (unsigned)m << 12;
      for (int s = 0; s < NSPLIT; ++s) {
        const unsigned b1 = pk1[(size_t)s * M + m];
        const unsigned b2 = pk2[(size_t)s * M + m];
        if ((int)(b2 >> 12) <= th) {          // group may hide a 3rd contender
          for (int r = 0; r < 64; ++r) pairs[base + r] = mh | (unsigned)(s * 64 + r);
          base += 64;
        } else if ((int)(b1 >> 12) <= th) {   // only stored winner qualifies
          pairs[base++] = mh | (b1 & 4095u);
        }
      }
    }
  }
}

// ---------------------------------------------------------------------------
// Kernel 4: exact fp64 rescore, one wave per pair, single pass.
// key = (bits(d2) & ~0xFFF) | row: atomicMin = argmin with low-index
// tie-break; 12 dropped mantissa bits = ~1e-9 abs tolerance (safe).
// ---------------------------------------------------------------------------
__global__ __launch_bounds__(256) void refine_score(
    const float* __restrict__ patches, const float* __restrict__ vocab,
    const unsigned* __restrict__ pairs, const int* __restrict__ paircount,
    unsigned long long* __restrict__ minkey) {
  const int lane = threadIdx.x & 63;
  const int gw = (blockIdx.x * 256 + threadIdx.x) >> 6;
  const int nw = (gridDim.x * 256) >> 6;
  int np = *paircount;
  if (np > PAIR_CAP) np = PAIR_CAP;
  for (int i = gw; i < np; i += nw) {
    const unsigned pr = pairs[i];
    const int m = pr >> 12, row = pr & 4095;
    const float4 pv = *(const float4*)(patches + (size_t)m * D + (lane << 2));
    const float4 vv = *(const float4*)(vocab + (size_t)row * D + (lane << 2));
    double acc = 0.0, df;
    df = (double)pv.x - (double)vv.x; acc = fma(df, df, acc);
    df = (double)pv.y - (double)vv.y; acc = fma(df, df, acc);
    df = (double)pv.z - (double)vv.z; acc = fma(df, df, acc);
    df = (double)pv.w - (double)vv.w; acc = fma(df, df, acc);
    #pragma unroll
    for (int off = 32; off > 0; off >>= 1) acc += __shfl_down(acc, off);
    if (lane == 0) {
      const unsigned long long key =
          ((unsigned long long)__double_as_longlong(acc) & ~0xFFFull) | (unsigned)row;
      atomicMin(&minkey[m], key);
    }
  }
}

// ---------------------------------------------------------------------------
// Kernel 5: write refined tokens (grid-stride over pairs; redundant same-value
// writes per flagged patch are benign).
// ---------------------------------------------------------------------------
__global__ __launch_bounds__(256) void refine_final(
    const unsigned* __restrict__ pairs, const int* __restrict__ paircount,
    const unsigned long long* __restrict__ minkey, float* __restrict__ tok) {
  int np = *paircount;
  if (np > PAIR_CAP) np = PAIR_CAP;
  for (int i = blockIdx.x * 256 + threadIdx.x; i < np; i += gridDim.x * 256) {
    const int m = pairs[i] >> 12;
    tok[m] = (float)(unsigned)(minkey[m] & 4095ull);
  }
}

// ---------------------------------------------------------------------------
extern "C" void kernel_launch(void* const* d_in, const int* in_sizes, int n_in,
                              void* d_out, int out_size, void* d_ws, size_t ws_size,
                              hipStream_t stream) {
  const float* images = (const float*)d_in[0];   // [64,256,256]
  const float* vocab  = (const float*)d_in[1];   // [4096,256]
  float* out     = (float*)d_out;
  float* patches = out;            // M*D floats
  float* tokens  = out + (size_t)M * D;

  // workspace layout (bytes):
  // Ah2 8MB | Vh2 2MB | v2 16KB | pk1 4MB | pk2 4MB | minkey 128KB |
  // paircount 64B | pairs 4MB   (~22.3 MB)
  char* ws = (char*)d_ws;
  _Float16* Ah2      = (_Float16*)(ws);
  _Float16* Vh2      = (_Float16*)(ws + 8388608);
  float*    v2       = (float*)   (ws + 10485760);
  unsigned* pk1      = (unsigned*)(ws + 10502144);
  unsigned* pk2      = (unsigned*)(ws + 14696448);
  unsigned long long* minkey = (unsigned long long*)(ws + 18890752);
  int*      paircount= (int*)     (ws + 19021824);
  unsigned* pairs    = (unsigned*)(ws + 19021888);

  prep_kernel<<<4096 + 1024, 256, 0, stream>>>(images, vocab, patches, Ah2,
                                               Vh2, v2, paircount);
  gemm_score_kernel<<<dim3(M / 64, V / 256), 256, 0, stream>>>(Ah2, Vh2, v2, pk1, pk2);
  reduce_gather_kernel<<<M / 256, 256, 0, stream>>>(pk1, pk2, tokens, minkey,
                                                    pairs, paircount);
  refine_score<<<256, 256, 0, stream>>>(patches, vocab, pairs, paircount, minkey);
  refine_final<<<32, 256, 0, stream>>>(pairs, paircount, minkey, tokens);
}

// Round 13
// 158.988 us; speedup vs baseline: 1.1005x; 1.1005x over previous
//
#include <hip/hip_runtime.h>
#include <math.h>

// Problem: images [64,256,256] f32 -> patches [16384][256] f32 (identity perm)
//          tokens [16384] = argmin_v ||patch - vocab[v]||^2, vocab [4096][256] f32
#define PS      16
#define D       256
#define V       4096
#define M       16384
#define NSPLIT  64              // V / 64 column groups
#define PAIR_CAP 1048576
// Scores packed as u32 keys: q = (u32)((s + 1024) * 512)  (20 bits), key =
// (q << 12) | col. min() on keys = argmin with lowest-index tie-break.
// fp16 score-diff error sigma ~3e-2; QMARGIN 130 quanta (=0.254) is ~8 sigma
// incl. trunc slack. Flagged (~4%) get exact fp64 on a candidate set provably
// containing the argmin.
#define QMARGIN 130

typedef _Float16 half8 __attribute__((ext_vector_type(8)));
typedef _Float16 half4 __attribute__((ext_vector_type(4)));
typedef float    f32x4 __attribute__((ext_vector_type(4)));

__device__ __forceinline__ void gload_lds16(const void* g, void* l) {
  __builtin_amdgcn_global_load_lds(
      (const __attribute__((address_space(1))) unsigned int*)g,
      (__attribute__((address_space(3))) unsigned int*)l, 16, 0, 0);
}

// Fragment-major layouts (halves):
//  Ah2[rowblk(256)][kt(8)][i(4)][q(4)][cl(16)][8] : row = rowblk*64+i*16+cl,
//      k = kt*32 + q*8 + h.   idx = rowblk*16384 + kt*2048 + i*512 + q*128 + cl*8 + h
//  Vh2[sp'(16)][kt(8)][jb(16)][q(4)][cl(16)][8]   : col = sp'*256+jb*16+cl,
//      k = kt*32 + q*8 + h.   idx = sp'*65536 + kt*8192 + jb*512 + q*128 + cl*8 + h

// ---------------------------------------------------------------------------
// Kernel 1: fused prep. Blocks [0,4096): patchify (float4) + fragment-major
// fp16 copy. Blocks [4096,5120): vocab fragment-major fp16 + v2.
// ---------------------------------------------------------------------------
__global__ __launch_bounds__(256) void prep_kernel(
    const float* __restrict__ img, const float* __restrict__ vocab,
    float* __restrict__ outp, _Float16* __restrict__ Ah2,
    _Float16* __restrict__ Vh2, float* __restrict__ v2,
    int* __restrict__ paircount) {
  if (blockIdx.x < 4096) {
    if (blockIdx.x == 0 && threadIdx.x == 0) *paircount = 0;
    const int t  = blockIdx.x * 256 + threadIdx.x;   // M*D/4 threads
    const int o4 = t << 2;
    const int m   = o4 >> 8;           // global patch index
    const int d   = o4 & 255;          // k (multiple of 4)
    const int b   = m >> 8;
    const int n   = m & 255;
    const int py = n >> 4, px = n & 15, i = d >> 4, j = d & 15;
    const float4 v = *(const float4*)(img + (b << 16) + ((py * PS + i) << 8) + px * PS + j);
    *(float4*)(outp + o4) = v;
    half4 h = { (_Float16)v.x, (_Float16)v.y, (_Float16)v.z, (_Float16)v.w };
    const int fa = (m >> 6) * 16384 + (d >> 5) * 2048 + ((m >> 4) & 3) * 512 +
                   ((d >> 3) & 3) * 128 + (m & 15) * 8 + (d & 7);
    *(half4*)(Ah2 + fa) = h;
  } else {
    const int gtid = (blockIdx.x - 4096) * 256 + threadIdx.x;
    const int c    = gtid >> 6;        // vocab row
    const int lane = gtid & 63;
    const int d0   = lane << 2;        // k (multiple of 4)
    const float4 v = *(const float4*)(vocab + (size_t)c * D + d0);
    half4 h = { (_Float16)v.x, (_Float16)v.y, (_Float16)v.z, (_Float16)v.w };
    const int fv = (c >> 8) * 65536 + (d0 >> 5) * 8192 + ((c >> 4) & 15) * 512 +
                   ((d0 >> 3) & 3) * 128 + (c & 15) * 8 + (d0 & 7);
    *(half4*)(Vh2 + fv) = h;
    float s = v.x * v.x + v.y * v.y + v.z * v.z + v.w * v.w;
    #pragma unroll
    for (int off = 32; off > 0; off >>= 1) s += __shfl_down(s, off);
    if (lane == 0) v2[c] = s;
  }
}

// ---------------------------------------------------------------------------
// Kernel 2: fp16 MFMA score GEMM, 32-col waves for occupancy.
// R12 lesson: limiter = per-wave serial load->wait->MFMA chain at only 4
// waves/SIMD (unified VGPR+AGPR: 48+64=112 <= 128 cap). Halving acc to
// acc[2][4]=32 cuts live regs to ~85 -> __launch_bounds__(256,5): 5
// waves/SIMD; LDS 32KB allows exactly 5 blocks/CU.
// Block = 64 rows x 128 cols (4 waves x 32 cols); grid (sp=32 FAST, rowblk)
// so consecutive blocks share the A-tile in L2. Transposed mfma (vocab=A-op)
// -> in-lane top-2 fold, 2-shuffle q-merge. Sibling waves (wid pairs) merge
// to 64-col groups via 4KB scratch carved from Af AFTER the K-loop, so the
// pk/reduce tail is unchanged from R12 (NSPLIT=64).
// ---------------------------------------------------------------------------
__global__ __launch_bounds__(256, 5) void gemm_score_kernel(
    const _Float16* __restrict__ Ah2,  // fragment-major, see layout above
    const _Float16* __restrict__ Vh2,
    const float* __restrict__ v2,
    unsigned* __restrict__ pk1, unsigned* __restrict__ pk2) {
  __shared__ __align__(16) _Float16 Af[8 * 64 * 32];  // 32 KB A tile (+ scratch after K-loop)

  const int tid  = threadIdx.x;
  const int lane = tid & 63;
  const int wid  = tid >> 6;
  const int sp     = blockIdx.x;            // 128-col block, FAST dim (A L2 reuse)
  const int rowblk = blockIdx.y;
  const int row0 = rowblk * 64;
  const int c0w  = sp * 128 + wid * 32;     // this wave's 32 vocab cols

  // ---- stage A tile: 8 x (64 lanes x 16B contiguous), one barrier ----
  {
    const _Float16* src = Ah2 + (size_t)rowblk * 16384 + wid * 4096 + lane * 8;
    _Float16* dst = Af + wid * 4096;        // wave-uniform; HW adds lane*16B
    #pragma unroll
    for (int t = 0; t < 8; ++t)
      gload_lds16(src + t * 512, dst + t * 512);
  }
  __syncthreads();

  const int cl = lane & 15;           // fragment row/col within 16
  const int q  = lane >> 4;           // quad: k-chunk selector
  const _Float16* Ak = Af + q * 128 + cl * 8;                    // patch frags (B-op)
  const _Float16* Bk = Vh2 + (c0w >> 8) * 65536 + ((c0w >> 4) & 15) * 512 +
                       q * 128 + cl * 8;                          // vocab frags (A-op)

  f32x4 acc[2][4];                    // [i = vocab tile][j = patch tile]
  #pragma unroll
  for (int i = 0; i < 2; ++i)
    #pragma unroll
    for (int j = 0; j < 4; ++j) acc[i][j] = (f32x4){0.f, 0.f, 0.f, 0.f};

  #pragma unroll 1                    // bound live set (R6 lesson)
  for (int kt = 0; kt < 8; ++kt) {
    half8 av[2], bp[4];
    #pragma unroll
    for (int i = 0; i < 2; ++i) av[i] = *(const half8*)(Bk + i * 512);
    #pragma unroll
    for (int j = 0; j < 4; ++j) bp[j] = *(const half8*)(Ak + j * 512);
    Bk += 8192; Ak += 2048;
    #pragma unroll
    for (int i = 0; i < 2; ++i)
      #pragma unroll
      for (int j = 0; j < 4; ++j)
        acc[i][j] = __builtin_amdgcn_mfma_f32_16x16x32_f16(av[i], bp[j], acc[i][j], 0, 0, 0);
  }

  // Epilogue (S^T). Lane (cl,q) holds, for patch row m = row0 + j*16 + cl,
  // scores of vocab cols v = c0w + i*16 + q*4 + r.
  // key_f = (score+1024)*512 = (v2+1024)*512 - 1024*acc
  float Cv[8];
  #pragma unroll
  for (int i = 0; i < 2; ++i) {
    const float4 vq = *(const float4*)(v2 + c0w + i * 16 + q * 4);
    #pragma unroll
    for (int r = 0; r < 4; ++r) Cv[i * 4 + r] = fmaf(vq[r], 512.0f, 524288.0f);
  }
  unsigned wk1[4], wk2[4];
  #pragma unroll
  for (int j = 0; j < 4; ++j) {
    unsigned K1 = 0xFFFFFFFFu, K2 = 0xFFFFFFFFu;
    #pragma unroll
    for (int i = 0; i < 2; ++i)
      #pragma unroll
      for (int r = 0; r < 4; ++r) {
        const unsigned key =
            ((unsigned)fmaf(-1024.0f, acc[i][j][r], Cv[i * 4 + r]) << 12) |
            (unsigned)(c0w + i * 16 + q * 4 + r);
        K2 = min(K2, max(K1, key));
        K1 = min(K1, key);
      }
    // merge across the 4 q-lanes holding this patch row (xor 16, 32)
    #pragma unroll
    for (int mask = 16; mask <= 32; mask <<= 1) {
      const unsigned o1 = (unsigned)__shfl_xor((int)K1, mask);
      const unsigned o2 = (unsigned)__shfl_xor((int)K2, mask);
      K2 = min(min(K2, o2), max(K1, o1));
      K1 = min(K1, o1);
    }
    wk1[j] = K1; wk2[j] = K2;
  }
  // ---- sibling-wave merge to 64-col groups via Af-as-scratch ----
  // scratch[pair(2)][w(2)][row(64)][2] u32 = 4KB inside Af (A reads all done)
  __syncthreads();                    // all waves finished ds_reads of Af
  unsigned* scr = (unsigned*)Af;
  if (q == 0) {
    #pragma unroll
    for (int j = 0; j < 4; ++j) {
      const int idx = (wid >> 1) * 256 + (wid & 1) * 128 + (j * 16 + cl) * 2;
      scr[idx] = wk1[j]; scr[idx + 1] = wk2[j];
    }
  }
  __syncthreads();
  if (tid < 128) {
    const int pair = tid >> 6, row = tid & 63;
    const unsigned a1 = scr[pair * 256 + row * 2], a2 = scr[pair * 256 + row * 2 + 1];
    const unsigned b1 = scr[pair * 256 + 128 + row * 2], b2 = scr[pair * 256 + 128 + row * 2 + 1];
    const unsigned K2 = min(min(a2, b2), max(a1, b1));
    const unsigned K1 = min(a1, b1);
    const int grp = sp * 2 + pair;
    pk1[(size_t)grp * M + row0 + row] = K1;
    pk2[(size_t)grp * M + row0 + row] = K2;
  }
}

// ---------------------------------------------------------------------------
// Kernel 3: merge NSPLIT partials -> token; flagged patches emit fp64-rescore
// candidate pairs. Parallelized 4x vs R12: 4 waves each scan 16 splits for
// 64 patches, LDS merge, wave 0 finishes (flag path rereads pk, ~4% only).
// ---------------------------------------------------------------------------
__global__ __launch_bounds__(256) void reduce_gather_kernel(
    const unsigned* __restrict__ pk1, const unsigned* __restrict__ pk2,
    float* __restrict__ tok, unsigned long long* __restrict__ minkey,
    unsigned* __restrict__ pairs, int* __restrict__ paircount) {
  __shared__ unsigned r1[4][64], r2[4][64];
  const int tid = threadIdx.x;
  const int mo  = tid & 63;
  const int wid = tid >> 6;
  const int m = blockIdx.x * 64 + mo;
  unsigned K1 = 0xFFFFFFFFu, K2 = 0xFFFFFFFFu;
  for (int s = wid * 16; s < wid * 16 + 16; ++s) {
    const unsigned b1 = pk1[(size_t)s * M + m];
    const unsigned b2 = pk2[(size_t)s * M + m];
    K2 = min(min(K2, b2), max(K1, b1));
    K1 = min(K1, b1);
  }
  r1[wid][mo] = K1; r2[wid][mo] = K2;
  __syncthreads();
  if (tid < 64) {
    K1 = 0xFFFFFFFFu; K2 = 0xFFFFFFFFu;
    #pragma unroll
    for (int w = 0; w < 4; ++w) {
      const unsigned b1 = r1[w][mo], b2 = r2[w][mo];
      K2 = min(min(K2, b2), max(K1, b1));
      K1 = min(K1, b1);
    }
    tok[m] = (float)(K1 & 4095u);
    minkey[m] = 0xFFFFFFFFFFFFFFFFull;
    if ((int)(K2 >> 12) - (int)(K1 >> 12) <= QMARGIN) {
      const int th = (int)(K1 >> 12) + QMARGIN;
      int cnt = 0;
      for (int s = 0; s < NSPLIT; ++s) {
        const unsigned b1 = pk1[(size_t)s * M + m];
        const unsigned b2 = pk2[(size_t)s * M + m];
        cnt += ((int)(b2 >> 12) <= th) ? 64
             : (((int)(b1 >> 12) <= th) ? 1 : 0);
      }
      int base = atomicAdd(paircount, cnt);
      if (base + cnt <= PAIR_CAP) {
        const unsigned mh = (unsigned)m << 12;
        for (int s = 0; s < NSPLIT; ++s) {
          const unsigned b1 = pk1[(size_t)s * M + m];
          const unsigned b2 = pk2[(size_t)s * M + m];
          if ((int)(b2 >> 12) <= th) {        // group may hide a 3rd contender
            for (int r = 0; r < 64; ++r) pairs[base + r] = mh | (unsigned)(s * 64 + r);
            base += 64;
          } else if ((int)(b1 >> 12) <= th) { // only stored winner qualifies
            pairs[base++] = mh | (b1 & 4095u);
          }
        }
      }
    }
  }
}

// ---------------------------------------------------------------------------
// Kernel 4: exact fp64 rescore, one wave per pair, single pass.
// key = (bits(d2) & ~0xFFF) | row: atomicMin = argmin with low-index
// tie-break; 12 dropped mantissa bits = ~1e-9 abs tolerance (safe).
// ---------------------------------------------------------------------------
__global__ __launch_bounds__(256) void refine_score(
    const float* __restrict__ patches, const float* __restrict__ vocab,
    const unsigned* __restrict__ pairs, const int* __restrict__ paircount,
    unsigned long long* __restrict__ minkey) {
  const int lane = threadIdx.x & 63;
  const int gw = (blockIdx.x * 256 + threadIdx.x) >> 6;
  const int nw = (gridDim.x * 256) >> 6;
  int np = *paircount;
  if (np > PAIR_CAP) np = PAIR_CAP;
  for (int i = gw; i < np; i += nw) {
    const unsigned pr = pairs[i];
    const int m = pr >> 12, row = pr & 4095;
    const float4 pv = *(const float4*)(patches + (size_t)m * D + (lane << 2));
    const float4 vv = *(const float4*)(vocab + (size_t)row * D + (lane << 2));
    double acc = 0.0, df;
    df = (double)pv.x - (double)vv.x; acc = fma(df, df, acc);
    df = (double)pv.y - (double)vv.y; acc = fma(df, df, acc);
    df = (double)pv.z - (double)vv.z; acc = fma(df, df, acc);
    df = (double)pv.w - (double)vv.w; acc = fma(df, df, acc);
    #pragma unroll
    for (int off = 32; off > 0; off >>= 1) acc += __shfl_down(acc, off);
    if (lane == 0) {
      const unsigned long long key =
          ((unsigned long long)__double_as_longlong(acc) & ~0xFFFull) | (unsigned)row;
      atomicMin(&minkey[m], key);
    }
  }
}

// ---------------------------------------------------------------------------
// Kernel 5: write refined tokens (grid-stride over pairs; redundant same-value
// writes per flagged patch are benign).
// ---------------------------------------------------------------------------
__global__ __launch_bounds__(256) void refine_final(
    const unsigned* __restrict__ pairs, const int* __restrict__ paircount,
    const unsigned long long* __restrict__ minkey, float* __restrict__ tok) {
  int np = *paircount;
  if (np > PAIR_CAP) np = PAIR_CAP;
  for (int i = blockIdx.x * 256 + threadIdx.x; i < np; i += gridDim.x * 256) {
    const int m = pairs[i] >> 12;
    tok[m] = (float)(unsigned)(minkey[m] & 4095ull);
  }
}

// ---------------------------------------------------------------------------
extern "C" void kernel_launch(void* const* d_in, const int* in_sizes, int n_in,
                              void* d_out, int out_size, void* d_ws, size_t ws_size,
                              hipStream_t stream) {
  const float* images = (const float*)d_in[0];   // [64,256,256]
  const float* vocab  = (const float*)d_in[1];   // [4096,256]
  float* out     = (float*)d_out;
  float* patches = out;            // M*D floats
  float* tokens  = out + (size_t)M * D;

  // workspace layout (bytes):
  // Ah2 8MB | Vh2 2MB | v2 16KB | pk1 4MB | pk2 4MB | minkey 128KB |
  // paircount 64B | pairs 4MB   (~22.3 MB)
  char* ws = (char*)d_ws;
  _Float16* Ah2      = (_Float16*)(ws);
  _Float16* Vh2      = (_Float16*)(ws + 8388608);
  float*    v2       = (float*)   (ws + 10485760);
  unsigned* pk1      = (unsigned*)(ws + 10502144);
  unsigned* pk2      = (unsigned*)(ws + 14696448);
  unsigned long long* minkey = (unsigned long long*)(ws + 18890752);
  int*      paircount= (int*)     (ws + 19021824);
  unsigned* pairs    = (unsigned*)(ws + 19021888);

  prep_kernel<<<4096 + 1024, 256, 0, stream>>>(images, vocab, patches, Ah2,
                                               Vh2, v2, paircount);
  gemm_score_kernel<<<dim3(V / 128, M / 64), 256, 0, stream>>>(Ah2, Vh2, v2, pk1, pk2);
  reduce_gather_kernel<<<M / 64, 256, 0, stream>>>(pk1, pk2, tokens, minkey,
                                                   pairs, paircount);
  refine_score<<<512, 256, 0, stream>>>(patches, vocab, pairs, paircount, minkey);
  refine_final<<<64, 256, 0, stream>>>(pairs, paircount, minkey, tokens);
}